// Round 7
// baseline (370.435 us; speedup 1.0000x reference)
//
#include <hip/hip_runtime.h>
#include <cstdint>
#include <cstddef>

// ---------- types ----------
typedef __attribute__((ext_vector_type(8))) short short8;        // MFMA bf16 A/B frag (4 VGPR)
typedef __attribute__((ext_vector_type(4))) float f32x4;         // MFMA C/D frag
typedef __attribute__((ext_vector_type(4))) unsigned short ushort4_t;

// RNE float->bf16 (finite inputs only)
__device__ __forceinline__ unsigned short f2bf(float f) {
  unsigned u = __float_as_uint(f);
  u += 0x7FFFu + ((u >> 16) & 1u);
  return (unsigned short)(u >> 16);
}

// async global->LDS, 16B per lane. LDS dest is wave-uniform base (+lane*16 implicit).
__device__ __forceinline__ void gload_lds16(const void* g, void* lds) {
  __builtin_amdgcn_global_load_lds((const __attribute__((address_space(1))) void*)g,
                                   (__attribute__((address_space(3))) void*)lds,
                                   16, 0, 0);
}

// Branch-free erf (A&S 7.1.26, abs err <= 1.5e-7), sign folded via bit ops.
__device__ __forceinline__ float erf_fast(float v) {
  float x = fabsf(v);
  float t = __builtin_amdgcn_rcpf(fmaf(0.3275911f, x, 1.0f));
  float p = fmaf(1.061405429f, t, -1.453152027f);
  p = fmaf(p, t, 1.421413741f);
  p = fmaf(p, t, -0.284496736f);
  p = fmaf(p, t, 0.254829592f);
  p = p * t;
  float e = fmaf(-p, __expf(-x * x), 1.0f);      // erf(|v|), >= 0
  unsigned s = __float_as_uint(v) & 0x80000000u;
  return __uint_as_float(__float_as_uint(e) | s);
}

// ---------- kernel 1: quantize x with per-channel s_a1 (symmetric, qn=-128 qp=127) ----------
__global__ void quant_x_kernel(const float4* __restrict__ x, const float* __restrict__ s_a1,
                               ushort4_t* __restrict__ xq, int n4, int c4mask) {
  const int stride = gridDim.x * blockDim.x;
  for (int i = blockIdx.x * blockDim.x + threadIdx.x; i < n4; i += stride) {
    float4 v = x[i];
    int c = (i & c4mask) << 2;           // channel base (C is pow2)
    float vv[4] = {v.x, v.y, v.z, v.w};
    ushort4_t o;
#pragma unroll
    for (int j = 0; j < 4; ++j) {
      float s = s_a1[c + j];
      float r = vv[j] / s;
      r = fminf(fmaxf(r, -128.f), 127.f);
      o[j] = f2bf(rintf(r) * s);
    }
    xq[i] = o;
  }
}

// ---------- kernel 2: statsq weight quant, one block (256 thr) per output row ----------
__global__ void quant_w_kernel(const float* __restrict__ w, unsigned short* __restrict__ wq,
                               int cols) {
  const int row = blockIdx.x;
  const float* wr = w + (size_t)row * cols;
  float part = 0.f;
  for (int j = threadIdx.x; j < cols; j += blockDim.x) part += fabsf(wr[j]);
#pragma unroll
  for (int o = 32; o > 0; o >>= 1) part += __shfl_down(part, o, 64);
  __shared__ float wsum[4];
  if ((threadIdx.x & 63) == 0) wsum[threadIdx.x >> 6] = part;
  __syncthreads();
  float mean = (wsum[0] + wsum[1] + wsum[2] + wsum[3]) / (float)cols;
  float s = 2.f * mean / sqrtf(127.f);
  unsigned short* wqr = wq + (size_t)row * cols;
  for (int j = threadIdx.x; j < cols; j += blockDim.x) {
    float r = wr[j] / s;
    r = fminf(fmaxf(r, -128.f), 127.f);
    wqr[j] = f2bf(rintf(r) * s);
  }
}

// ---------- m201-paced 256x256 GEMM (A: MxK rm, B: NxK rm) ----------
// 4 phases per K-tile, each: {ds_read (8 or 4 b128) | stage 1 half-tile |
// (vmcnt@ph4) | BAR | lgkm0 | setprio1 16xMFMA setprio0 | BAR}.
// Balanced reads via B-column split: wave wc covers cols wc*32 (staged-half0, b0)
// and 128+wc*32 (staged-half1, b1); b0(t+1) read one phase early (ph4, other buf).
// Stage slots (tile t stages t+2 into cur): B0@ph1, A0@ph2, A1@ph3, B1@ph4 —
// each >=1 closing-barrier after that region's last read (b0(t): ph4(t-1);
// a0: ph1; a1: ph2; b1: ph3). vmcnt(6) at ph4 provably drains {A0,A1,B1}(t+1)
// + B0(t+2) before any of their reads; tail: vmcnt(0) at t==nkt-2.
#define BAR() __builtin_amdgcn_s_barrier()
#define SB() __builtin_amdgcn_sched_barrier(0)
#define LGKM0() { asm volatile("s_waitcnt lgkmcnt(0)" ::: "memory"); SB(); }
#define PRIO1() __builtin_amdgcn_s_setprio(1)
#define PRIO0() __builtin_amdgcn_s_setprio(0)

#define STG(gbase, ldsbuf, h, kt) { \
  _Pragma("unroll") for (int i_ = 0; i_ < 2; ++i_) { \
    const int rb_ = (h) * 128 + (w * 2 + i_) * 8; \
    gload_lds16((gbase) + (size_t)rb_ * K + (size_t)(kt) * 64, (void*)((ldsbuf) + rb_ * 64)); } }

#define LDA_(dst, buf, mh) { \
  _Pragma("unroll") for (int mi_ = 0; mi_ < 4; ++mi_) { \
    dst[mi_][0] = *(const short8*)((buf) + aBase + (mh) * 4096 + mi_ * 1024 + ck0); \
    dst[mi_][1] = *(const short8*)((buf) + aBase + (mh) * 4096 + mi_ * 1024 + ck1); } }

#define LDBX(dst, buf, base) { \
  _Pragma("unroll") for (int ni_ = 0; ni_ < 2; ++ni_) { \
    dst[ni_][0] = *(const short8*)((buf) + (base) + ni_ * 1024 + ck0); \
    dst[ni_][1] = *(const short8*)((buf) + (base) + ni_ * 1024 + ck1); } }

#define MMQ(aR, bR, mh, nh) { \
  _Pragma("unroll") for (int kk_ = 0; kk_ < 2; ++kk_) \
  _Pragma("unroll") for (int mi_ = 0; mi_ < 4; ++mi_) \
  _Pragma("unroll") for (int ni_ = 0; ni_ < 2; ++ni_) \
    acc[(mh) * 4 + mi_][(nh) * 2 + ni_] = __builtin_amdgcn_mfma_f32_16x16x32_bf16( \
        aR[mi_][kk_], bR[ni_][kk_], acc[(mh) * 4 + mi_][(nh) * 2 + ni_], 0, 0, 0); }

template <int EPI>
__global__ __launch_bounds__(512, 2) void gemm_bt_m2(
    const unsigned short* __restrict__ A, const unsigned short* __restrict__ B,
    const float* __restrict__ bias, const float* __restrict__ s2,
    const float* __restrict__ beta, unsigned short* __restrict__ Cq,
    float* __restrict__ Cf, int N, int K)
{
  __shared__ __align__(16) unsigned short As0[256 * 64];
  __shared__ __align__(16) unsigned short As1[256 * 64];
  __shared__ __align__(16) unsigned short Bs0[256 * 64];
  __shared__ __align__(16) unsigned short Bs1[256 * 64];

  const int tid = threadIdx.x;
  const int w = tid >> 6, ll = tid & 63;
  const int wr = w >> 2, wc = w & 3;

  // T1: bijective XCD swizzle, y-major slab order (nwg % 8 == 0 for our grids)
  const int nwg = gridDim.x * gridDim.y;
  const int bid = blockIdx.x + gridDim.x * blockIdx.y;
  const int cpx = nwg >> 3;
  const int swz = (bid & 7) * cpx + (bid >> 3);
  const int gy = gridDim.y;
  const int bx = swz / gy, by = swz - bx * gy;   // y fastest within slab
  const long bm = (long)bx * 256;
  const long bn = (long)by * 256;

  // staging source (pre-swizzled so linear LDS dest + XOR read = consistent, rule #21)
  const int srow = ll >> 3;
  const int scol = ((ll & 7) ^ srow) << 3;
  const unsigned short* Agl = A + ((size_t)bm + srow) * K + scol;
  const unsigned short* Bgl = B + ((size_t)bn + srow) * K + scol;

  // per-lane ds_read offsets (u16 elems)
  const int lhi = ll >> 4, llo = ll & 15, l7 = ll & 7;
  const int ck0 = ((0 * 4 + lhi) ^ l7) * 8;
  const int ck1 = ((1 * 4 + lhi) ^ l7) * 8;
  const int aBase = (wr * 128 + llo) * 64;
  const int bBase0 = (wc * 32 + llo) * 64;          // b0 strip: staged-half0
  const int bBase1 = (128 + wc * 32 + llo) * 64;    // b1 strip: staged-half1

  f32x4 acc[8][4] = {};
  short8 a0[4][2], a1[4][2], b0[2][2], b1[2][2];

  const int nkt = K >> 6;   // 16 (GEMM1) or 64 (GEMM2), >= 4

  // ---- prologue: stage t0 -> buf0, t1 -> buf1; prove t0; read b0(0) ----
  STG(Bgl, Bs0, 0, 0); STG(Agl, As0, 0, 0); STG(Agl, As0, 1, 0); STG(Bgl, Bs0, 1, 0);
  STG(Bgl, Bs1, 0, 1); STG(Agl, As1, 0, 1); STG(Agl, As1, 1, 1); STG(Bgl, Bs1, 1, 1);
  asm volatile("s_waitcnt vmcnt(8)" ::: "memory"); SB();   // t0's 8 drained; t1 in flight
  BAR();
  LDBX(b0, Bs0, bBase0);            // b0(0) pre-read
  LGKM0();                          // drained before any re-stage of this region
  BAR();

  for (int t = 0; t < nkt; ++t) {
    unsigned short* Asb = (t & 1) ? As1 : As0;
    unsigned short* Bsb = (t & 1) ? Bs1 : Bs0;
    unsigned short* Bsn = (t & 1) ? Bs0 : Bs1;   // other buffer (tile t+1)
    const bool i1 = (t + 1 < nkt), i2 = (t + 2 < nkt);

    // ph1: read a0 (8); stage B-half0(t+2); MFMA q(0,0)=a0*b0
    LDA_(a0, Asb, 0);
    if (i2) STG(Bgl, Bsb, 0, t + 2);
    BAR(); LGKM0();
    PRIO1(); MMQ(a0, b0, 0, 0); PRIO0();
    BAR();

    // ph2: read a1 (8); stage A-half0(t+2); MFMA q(1,0)=a1*b0
    LDA_(a1, Asb, 1);
    if (i2) STG(Agl, Asb, 0, t + 2);
    BAR(); LGKM0();
    PRIO1(); MMQ(a1, b0, 1, 0); PRIO0();
    BAR();

    // ph3: read b1 (4); stage A-half1(t+2); MFMA q(1,1)=a1*b1
    LDBX(b1, Bsb, bBase1);
    if (i2) STG(Agl, Asb, 1, t + 2);
    BAR(); LGKM0();
    PRIO1(); MMQ(a1, b1, 1, 1); PRIO0();
    BAR();

    // ph4: read b0(t+1) (4, other buf); stage B-half1(t+2); vmcnt; MFMA q(0,1)=a0*b1
    if (i1) LDBX(b0, Bsn, bBase0);
    if (i2) STG(Bgl, Bsb, 1, t + 2);
    if (i2)      { asm volatile("s_waitcnt vmcnt(6)" ::: "memory"); SB(); }
    else if (i1) { asm volatile("s_waitcnt vmcnt(0)" ::: "memory"); SB(); }
    BAR(); LGKM0();
    PRIO1(); MMQ(a0, b1, 0, 1); PRIO0();
    BAR();
  }

  // ---- epilogue; C/D layout: col = lane&15, row = (lane>>4)*4 + reg ----
  // NI 0,1 -> cols bn + wc*32 + NI*16 ; NI 2,3 -> cols bn + 128 + wc*32 + (NI-2)*16
  const int lr = lhi;
  const int lc = llo;
#pragma unroll
  for (int NI = 0; NI < 4; ++NI) {
    const long col = bn + wc * 32 + ((NI >= 2) ? 128 : 0) + (NI & 1) * 16 + lc;
    const float bv = bias[col];
    float sv = 1.f, bev = 0.f, inv = 1.f;
    if (EPI == 0) { sv = s2[col]; bev = beta[col]; inv = 1.0f / sv; }
#pragma unroll
    for (int MI = 0; MI < 8; ++MI) {
#pragma unroll
      for (int r = 0; r < 4; ++r) {
        const size_t rowg = (size_t)(bm + wr * 128 + MI * 16 + lr * 4 + r);
        float v = acc[MI][NI][r] + bv;
        if (EPI == 0) {
          float g = 0.5f * v * (1.f + erf_fast(v * 0.70710678118654752f));
          float rr = (g - bev) * inv;
          rr = fminf(fmaxf(rr, 0.f), 255.f);
          Cq[rowg * N + col] = f2bf(fmaf(rintf(rr), sv, bev));
        } else {
          Cf[rowg * N + col] = v;
        }
      }
    }
  }
}

// ---------- launch ----------
extern "C" void kernel_launch(void* const* d_in, const int* in_sizes, int n_in,
                              void* d_out, int out_size, void* d_ws, size_t ws_size,
                              hipStream_t stream) {
  const float* x     = (const float*)d_in[0];
  const float* w1    = (const float*)d_in[1];
  const float* b1    = (const float*)d_in[2];
  const float* w2    = (const float*)d_in[3];
  const float* b2    = (const float*)d_in[4];
  const float* s_a1  = (const float*)d_in[5];
  const float* s_a2  = (const float*)d_in[6];
  const float* beta2 = (const float*)d_in[7];
  float* out = (float*)d_out;

  const int C = 1024, H = 4096;
  const int M = in_sizes[0] / C;  // 16384

  // workspace layout (bf16 bit-patterns as u16): xq | wq1 | wq2 | hq
  unsigned short* xq  = (unsigned short*)d_ws;
  unsigned short* wq1 = xq  + (size_t)M * C;
  unsigned short* wq2 = wq1 + (size_t)H * C;
  unsigned short* hq  = wq2 + (size_t)C * H;

  quant_x_kernel<<<2048, 256, 0, stream>>>((const float4*)x, s_a1, (ushort4_t*)xq,
                                           M * C / 4, C / 4 - 1);
  quant_w_kernel<<<H, 256, 0, stream>>>(w1, wq1, C);
  quant_w_kernel<<<C, 256, 0, stream>>>(w2, wq2, H);

  dim3 g1(M / 256, H / 256);  // 64 x 16
  gemm_bt_m2<0><<<g1, 512, 0, stream>>>(xq, wq1, b1, s_a2, beta2, hq, nullptr, H, C);
  dim3 g2(M / 256, C / 256);  // 64 x 4
  gemm_bt_m2<1><<<g2, 512, 0, stream>>>(hq, wq2, b2, nullptr, nullptr, nullptr, out, C, H);
}

// Round 9
// 363.866 us; speedup vs baseline: 1.0181x; 1.0181x over previous
//
#include <hip/hip_runtime.h>
#include <cstdint>
#include <cstddef>

// ---------- types ----------
typedef __attribute__((ext_vector_type(8))) short short8;        // MFMA bf16 A/B frag (4 VGPR)
typedef __attribute__((ext_vector_type(4))) float f32x4;         // MFMA C/D frag
typedef __attribute__((ext_vector_type(4))) unsigned short ushort4_t;

// RNE float->bf16 (finite inputs only)
__device__ __forceinline__ unsigned short f2bf(float f) {
  unsigned u = __float_as_uint(f);
  u += 0x7FFFu + ((u >> 16) & 1u);
  return (unsigned short)(u >> 16);
}

// async global->LDS, 16B per lane. LDS dest is wave-uniform base (+lane*16 implicit).
__device__ __forceinline__ void gload_lds16(const void* g, void* lds) {
  __builtin_amdgcn_global_load_lds((const __attribute__((address_space(1))) void*)g,
                                   (__attribute__((address_space(3))) void*)lds,
                                   16, 0, 0);
}

// Branch-free erf (A&S 7.1.26, abs err <= 1.5e-7), sign folded via bit ops.
__device__ __forceinline__ float erf_fast(float v) {
  float x = fabsf(v);
  float t = __builtin_amdgcn_rcpf(fmaf(0.3275911f, x, 1.0f));
  float p = fmaf(1.061405429f, t, -1.453152027f);
  p = fmaf(p, t, 1.421413741f);
  p = fmaf(p, t, -0.284496736f);
  p = fmaf(p, t, 0.254829592f);
  p = p * t;
  float e = fmaf(-p, __expf(-x * x), 1.0f);      // erf(|v|), >= 0
  unsigned s = __float_as_uint(v) & 0x80000000u;
  return __uint_as_float(__float_as_uint(e) | s);
}

// ---------- kernel 1: quantize x with per-channel s_a1 (symmetric, qn=-128 qp=127) ----------
__global__ void quant_x_kernel(const float4* __restrict__ x, const float* __restrict__ s_a1,
                               ushort4_t* __restrict__ xq, int n4, int c4mask) {
  const int stride = gridDim.x * blockDim.x;
  for (int i = blockIdx.x * blockDim.x + threadIdx.x; i < n4; i += stride) {
    float4 v = x[i];
    int c = (i & c4mask) << 2;           // channel base (C is pow2)
    float vv[4] = {v.x, v.y, v.z, v.w};
    ushort4_t o;
#pragma unroll
    for (int j = 0; j < 4; ++j) {
      float s = s_a1[c + j];
      float r = vv[j] / s;
      r = fminf(fmaxf(r, -128.f), 127.f);
      o[j] = f2bf(rintf(r) * s);
    }
    xq[i] = o;
  }
}

// ---------- kernel 2: statsq weight quant, one block (256 thr) per output row ----------
__global__ void quant_w_kernel(const float* __restrict__ w, unsigned short* __restrict__ wq,
                               int cols) {
  const int row = blockIdx.x;
  const float* wr = w + (size_t)row * cols;
  float part = 0.f;
  for (int j = threadIdx.x; j < cols; j += blockDim.x) part += fabsf(wr[j]);
#pragma unroll
  for (int o = 32; o > 0; o >>= 1) part += __shfl_down(part, o, 64);
  __shared__ float wsum[4];
  if ((threadIdx.x & 63) == 0) wsum[threadIdx.x >> 6] = part;
  __syncthreads();
  float mean = (wsum[0] + wsum[1] + wsum[2] + wsum[3]) / (float)cols;
  float s = 2.f * mean / sqrtf(127.f);
  unsigned short* wqr = wq + (size_t)row * cols;
  for (int j = threadIdx.x; j < cols; j += blockDim.x) {
    float r = wr[j] / s;
    r = fminf(fmaxf(r, -128.f), 127.f);
    wqr[j] = f2bf(rintf(r) * s);
  }
}

// ---------- 4-phase continuous-feed 256x256 GEMM (A: MxK rm, B: NxK rm) ----------
// Phase p = {vmcnt | BAR | ds_read batch | STG slot | lgkm wait | 16 MFMA}.
// Gray-code quadrants q00,q01,q11,q10; reads spread 4/8/8/4; stages 1 half-tile/phase.
// TAIL FIX (round-8 race, root-caused): at t=nkt-2 i2 is false (p2 stage skipped),
// so outstanding VMEM at p3 is 8 not 10 -> VMC(6) left Ah0(nkt-1) unproven and
// VMC(4) left Bh1(nkt-1) unproven (staged only 3 phases before its read) ->
// intermittent replay corruption. Fix: i2 ? counted : vmcnt(0) at p3/p4.
// Steady-state FIFO audit (unchanged): at p3, outstanding 10 = {Bh0,Ah0,Ah1}(t+1)
// +{Bh1(t+1),Bh0(t+2)}; VMC(6) drains Bh0,Ah0(t+1) before a0(t+1) read. At p4,
// 8 outstanding after p3's stage; VMC(4) drains Ah1,Bh1(t+1) before b1(t+1) read.
// vmcnt-before-BAR makes per-wave proof block-wide (all waves same load counts).
// LDS WAR: every STG slot lands >=1 BAR after the block-wide lgkm-drain of that
// region's last reads (b0/a0/b1 @ p1 LGKM(0); a1 @ p3 LGKM(8)).
#define BAR() { asm volatile("" ::: "memory"); __builtin_amdgcn_s_barrier(); asm volatile("" ::: "memory"); }
#define SB() __builtin_amdgcn_sched_barrier(0)
#define LGKM(n) { asm volatile("s_waitcnt lgkmcnt(" #n ")" ::: "memory"); SB(); }
#define VMC(n) { asm volatile("s_waitcnt vmcnt(" #n ")" ::: "memory"); SB(); }
#define PRIO1() __builtin_amdgcn_s_setprio(1)
#define PRIO0() __builtin_amdgcn_s_setprio(0)

#define STG(gbase, ldsbuf, h, kt) { \
  _Pragma("unroll") for (int i_ = 0; i_ < 2; ++i_) { \
    const int rb_ = (h) * 128 + (w * 2 + i_) * 8; \
    gload_lds16((gbase) + (size_t)rb_ * K + (size_t)(kt) * 64, (void*)((ldsbuf) + rb_ * 64)); } }

#define LDA_(dst, buf, mh) { \
  _Pragma("unroll") for (int mi_ = 0; mi_ < 4; ++mi_) { \
    dst[mi_][0] = *(const short8*)((buf) + aBase + (mh) * 4096 + mi_ * 1024 + ck0); \
    dst[mi_][1] = *(const short8*)((buf) + aBase + (mh) * 4096 + mi_ * 1024 + ck1); } }

#define LDBX(dst, buf, base) { \
  _Pragma("unroll") for (int ni_ = 0; ni_ < 2; ++ni_) { \
    dst[ni_][0] = *(const short8*)((buf) + (base) + ni_ * 1024 + ck0); \
    dst[ni_][1] = *(const short8*)((buf) + (base) + ni_ * 1024 + ck1); } }

#define MMQ(aR, bR, mh, nh) { \
  _Pragma("unroll") for (int kk_ = 0; kk_ < 2; ++kk_) \
  _Pragma("unroll") for (int mi_ = 0; mi_ < 4; ++mi_) \
  _Pragma("unroll") for (int ni_ = 0; ni_ < 2; ++ni_) \
    acc[(mh) * 4 + mi_][(nh) * 2 + ni_] = __builtin_amdgcn_mfma_f32_16x16x32_bf16( \
        aR[mi_][kk_], bR[ni_][kk_], acc[(mh) * 4 + mi_][(nh) * 2 + ni_], 0, 0, 0); }

template <int EPI>
__global__ __launch_bounds__(512, 2) void gemm_bt_cf(
    const unsigned short* __restrict__ A, const unsigned short* __restrict__ B,
    const float* __restrict__ bias, const float* __restrict__ s2,
    const float* __restrict__ beta, unsigned short* __restrict__ Cq,
    float* __restrict__ Cf, int N, int K)
{
  __shared__ __align__(16) unsigned short As0[256 * 64];
  __shared__ __align__(16) unsigned short As1[256 * 64];
  __shared__ __align__(16) unsigned short Bs0[256 * 64];
  __shared__ __align__(16) unsigned short Bs1[256 * 64];

  const int tid = threadIdx.x;
  const int w = tid >> 6, ll = tid & 63;
  const int wr = w >> 2, wc = w & 3;

  // T1: bijective XCD swizzle, y-major slab order (nwg % 8 == 0 for our grids)
  const int nwg = gridDim.x * gridDim.y;
  const int bid = blockIdx.x + gridDim.x * blockIdx.y;
  const int cpx = nwg >> 3;
  const int swz = (bid & 7) * cpx + (bid >> 3);
  const int gy = gridDim.y;
  const int bx = swz / gy, by = swz - bx * gy;   // y fastest within slab
  const long bm = (long)bx * 256;
  const long bn = (long)by * 256;

  // staging source (pre-swizzled so linear LDS dest + XOR read = consistent, rule #21)
  const int srow = ll >> 3;
  const int scol = ((ll & 7) ^ srow) << 3;
  const unsigned short* Agl = A + ((size_t)bm + srow) * K + scol;
  const unsigned short* Bgl = B + ((size_t)bn + srow) * K + scol;

  // per-lane ds_read offsets (u16 elems)
  const int lhi = ll >> 4, llo = ll & 15, l7 = ll & 7;
  const int ck0 = ((0 * 4 + lhi) ^ l7) * 8;
  const int ck1 = ((1 * 4 + lhi) ^ l7) * 8;
  const int aBase = (wr * 128 + llo) * 64;
  const int bBase0 = (wc * 32 + llo) * 64;          // b0 strip: staged-half0
  const int bBase1 = (128 + wc * 32 + llo) * 64;    // b1 strip: staged-half1

  f32x4 acc[8][4] = {};
  short8 a0[4][2], a1[4][2], b0[2][2], b1[2][2];

  const int nkt = K >> 6;   // 16 (GEMM1) or 64 (GEMM2), >= 4

  // ---- prologue: stage t0 fully + {Bh0,Ah0,Ah1}(t1) in slot-FIFO order ----
  STG(Bgl, Bs0, 0, 0); STG(Agl, As0, 0, 0); STG(Agl, As0, 1, 0); STG(Bgl, Bs0, 1, 0);
  STG(Bgl, Bs1, 0, 1); STG(Agl, As1, 0, 1); STG(Agl, As1, 1, 1);
  VMC(6);                           // t0's 8 drained; {Bh0,Ah0,Ah1}(t1) in flight
  BAR();
  LDA_(a0, As0, 0); SB();           // a0(0): 8 reads
  LDBX(b1, Bs0, bBase1); SB();      // b1(0): 4 reads

  for (int t = 0; t < nkt; ++t) {
    unsigned short* Asb = (t & 1) ? As1 : As0;
    unsigned short* Bsb = (t & 1) ? Bs1 : Bs0;
    unsigned short* Asn = (t & 1) ? As0 : As1;
    unsigned short* Bsn = (t & 1) ? Bs0 : Bs1;
    const bool i1 = (t + 1 < nkt), i2 = (t + 2 < nkt);

    // p1: read b0(t); stage Bh1(t+1)->other; wait all; q00 = a0*b0
    BAR();
    LDBX(b0, Bsb, bBase0); SB();
    if (i1) STG(Bgl, Bsn, 1, t + 1);
    LGKM(0);
    PRIO1(); MMQ(a0, b0, 0, 0); PRIO0();

    // p2: read a1(t); stage Bh0(t+2)->cur; q01 = a0*b1 (operands already drained)
    BAR();
    LDA_(a1, Asb, 1); SB();
    if (i2) STG(Bgl, Bsb, 0, t + 2);
    PRIO1(); MMQ(a0, b1, 0, 1); PRIO0();

    // p3: prove Ah0(t+1) landed (tail: drain ALL); read a0(t+1); stage Ah0(t+2); q11
    if (i2) { VMC(6); } else { VMC(0); }
    BAR();
    if (i1) { LDA_(a0, Asn, 0); SB(); }
    if (i2) STG(Agl, Asb, 0, t + 2);
    if (i1) { LGKM(8); } else { LGKM(0); }
    PRIO1(); MMQ(a1, b1, 1, 1); PRIO0();

    // p4: prove Bh1(t+1) landed (tail: drain ALL); read b1(t+1); stage Ah1(t+2); q10
    if (i2) { VMC(4); } else { VMC(0); }
    BAR();
    if (i1) { LDBX(b1, Bsn, bBase1); SB(); }
    if (i2) STG(Agl, Asb, 1, t + 2);
    PRIO1(); MMQ(a1, b0, 1, 0); PRIO0();
  }

  // ---- epilogue; C/D layout: col = lane&15, row = (lane>>4)*4 + reg ----
  // NI 0,1 -> cols bn + wc*32 + NI*16 ; NI 2,3 -> cols bn + 128 + wc*32 + (NI-2)*16
  const int lr = lhi;
  const int lc = llo;
#pragma unroll
  for (int NI = 0; NI < 4; ++NI) {
    const long col = bn + wc * 32 + ((NI >= 2) ? 128 : 0) + (NI & 1) * 16 + lc;
    const float bv = bias[col];
    float sv = 1.f, bev = 0.f, inv = 1.f;
    if (EPI == 0) { sv = s2[col]; bev = beta[col]; inv = 1.0f / sv; }
#pragma unroll
    for (int MI = 0; MI < 8; ++MI) {
#pragma unroll
      for (int r = 0; r < 4; ++r) {
        const size_t rowg = (size_t)(bm + wr * 128 + MI * 16 + lr * 4 + r);
        float v = acc[MI][NI][r] + bv;
        if (EPI == 0) {
          float g = 0.5f * v * (1.f + erf_fast(v * 0.70710678118654752f));
          float rr = (g - bev) * inv;
          rr = fminf(fmaxf(rr, 0.f), 255.f);
          Cq[rowg * N + col] = f2bf(fmaf(rintf(rr), sv, bev));
        } else {
          Cf[rowg * N + col] = v;
        }
      }
    }
  }
}

// ---------- launch ----------
extern "C" void kernel_launch(void* const* d_in, const int* in_sizes, int n_in,
                              void* d_out, int out_size, void* d_ws, size_t ws_size,
                              hipStream_t stream) {
  const float* x     = (const float*)d_in[0];
  const float* w1    = (const float*)d_in[1];
  const float* b1    = (const float*)d_in[2];
  const float* w2    = (const float*)d_in[3];
  const float* b2    = (const float*)d_in[4];
  const float* s_a1  = (const float*)d_in[5];
  const float* s_a2  = (const float*)d_in[6];
  const float* beta2 = (const float*)d_in[7];
  float* out = (float*)d_out;

  const int C = 1024, H = 4096;
  const int M = in_sizes[0] / C;  // 16384

  // workspace layout (bf16 bit-patterns as u16): xq | wq1 | wq2 | hq
  unsigned short* xq  = (unsigned short*)d_ws;
  unsigned short* wq1 = xq  + (size_t)M * C;
  unsigned short* wq2 = wq1 + (size_t)H * C;
  unsigned short* hq  = wq2 + (size_t)C * H;

  quant_x_kernel<<<2048, 256, 0, stream>>>((const float4*)x, s_a1, (ushort4_t*)xq,
                                           M * C / 4, C / 4 - 1);
  quant_w_kernel<<<H, 256, 0, stream>>>(w1, wq1, C);
  quant_w_kernel<<<C, 256, 0, stream>>>(w2, wq2, H);

  dim3 g1(M / 256, H / 256);  // 64 x 16
  gemm_bt_cf<0><<<g1, 512, 0, stream>>>(xq, wq1, b1, s_a2, beta2, hq, nullptr, H, C);
  dim3 g2(M / 256, C / 256);  // 64 x 4
  gemm_bt_cf<1><<<g2, 512, 0, stream>>>(hq, wq2, b2, nullptr, nullptr, nullptr, out, C, H);
}